// Round 16
// baseline (427.702 us; speedup 1.0000x reference)
//
#include <hip/hip_runtime.h>
#include <cstddef>
#include <cstdint>

#define B_  2
#define N_  2048
#define M_  8192
#define C1_ 256
#define C_  128
#define K_  16
#define CS_ 16

// 1/sqrt(1+1e-5)
#define BNINV 0.9999950000374997f

// fat-kernel role partition: 4096 kNN blocks split across three fat kernels
#define KNN1 1024
#define KNN2 2048
#define KNN3 1024
#define FB    (B_*N_/64)    // 64   k_f blocks
#define TNNB  (B_*M_/4)     // 4096 three_nn blocks
#define FEATB (B_*M_/64)    // 256  k_feat blocks
#define LQKVB (B_*M_/64)    // 256  k_lqkv blocks

// ======================= tiled fp32 GEMM machinery =========================
// BM=64, BN=128, BK=32, 256 threads, 4x8 micro-tile per thread.
#define LDSA 17   // float4 stride of A k-row (64 f + 4 pad)
#define LDSB 33   // float4 stride of B k-row (128 f + 4 pad)

__device__ __forceinline__ void stage_direct64(float4* Ls4, const float4* src4,
                                               size_t row_stride4, int k0,
                                               size_t col0_4, int t)
{
#pragma unroll
    for (int i = 0; i < 2; ++i) {
        int idx = t + i * 256;
        int kk = idx >> 4, f4 = idx & 15;
        Ls4[kk * LDSA + f4] = src4[(size_t)(k0 + kk) * row_stride4 + col0_4 + f4];
    }
}

__device__ __forceinline__ void stage_transposeA(float* Lsf, const float* src,
                                                 int row0, int ldk, int k0, int t)
{
    int u = t & 7, r = t >> 3;
#pragma unroll
    for (int i = 0; i < 2; ++i) {
        int row = r + i * 32;
        float4 v = *(const float4*)(src + (size_t)(row0 + row) * ldk + k0 + u * 4);
        Lsf[(u * 4 + 0) * 68 + row] = v.x;
        Lsf[(u * 4 + 1) * 68 + row] = v.y;
        Lsf[(u * 4 + 2) * 68 + row] = v.z;
        Lsf[(u * 4 + 3) * 68 + row] = v.w;
    }
}

__device__ __forceinline__ void stage_transposeB(float* Lsf, const float* src,
                                                 int ldk, int k0, int t)
{
    int u = t & 7, r = t >> 3;
#pragma unroll
    for (int i = 0; i < 4; ++i) {
        int row = r + i * 32;
        float4 v = *(const float4*)(src + (size_t)row * ldk + k0 + u * 4);
        Lsf[(u * 4 + 0) * 132 + row] = v.x;
        Lsf[(u * 4 + 1) * 132 + row] = v.y;
        Lsf[(u * 4 + 2) * 132 + row] = v.z;
        Lsf[(u * 4 + 3) * 132 + row] = v.w;
    }
}

__device__ __forceinline__ void gemm_step64(const float4* As4, const float4* Bs4,
                                            int tm, int tn, float acc[4][8])
{
#pragma unroll 4
    for (int kk = 0; kk < 32; ++kk) {
        float4 a0 = As4[kk * LDSA + tm];
        float4 b0 = Bs4[kk * LDSB + tn * 2];
        float4 b1 = Bs4[kk * LDSB + tn * 2 + 1];
        float av[4] = {a0.x,a0.y,a0.z,a0.w};
        float bv[8] = {b0.x,b0.y,b0.z,b0.w,b1.x,b1.y,b1.z,b1.w};
#pragma unroll
        for (int i = 0; i < 4; ++i)
#pragma unroll
            for (int j = 0; j < 8; ++j)
                acc[i][j] = fmaf(av[i], bv[j], acc[i][j]);
    }
}

__device__ __forceinline__ void load8(const float* p, float* v)
{
    float4 a = *(const float4*)p, b = *(const float4*)(p + 4);
    v[0]=a.x; v[1]=a.y; v[2]=a.z; v[3]=a.w; v[4]=b.x; v[5]=b.y; v[6]=b.z; v[7]=b.w;
}
__device__ __forceinline__ void store8(float* p, const float* v)
{
    *(float4*)p       = make_float4(v[0],v[1],v[2],v[3]);
    *(float4*)(p + 4) = make_float4(v[4],v[5],v[6],v[7]);
}

// ======================== role bodies (device funcs) =======================

// --- kNN: one wave per query (lane-min merge + bitonic seed), 135us/4096blk ---
__device__ void knn_body(const float* __restrict__ cx, const float* __restrict__ cy,
                         const float* __restrict__ cz, int* __restrict__ out_knn,
                         int qblock, int tid)
{
    int q    = qblock * 4 + (tid >> 6);
    int lane = tid & 63;
    int b    = q >> 13;
    const float4* bx4 = (const float4*)(cx + (size_t)b * M_);
    const float4* by4 = (const float4*)(cy + (size_t)b * M_);
    const float4* bz4 = (const float4*)(cz + (size_t)b * M_);
    float qx = cx[q], qy = cy[q], qz = cz[q];

    unsigned long long list = ~0ULL;
    unsigned long long tau  = ~0ULL;
    float taud = 3e38f;

#define DIST(px,py,pz) ({ \
    float dx = (px)-qx, dy = (py)-qy, dz = (pz)-qz; \
    __fadd_rn(__fadd_rn(__fmul_rn(dx,dx), __fmul_rn(dy,dy)), __fmul_rn(dz,dz)); })

#define MIN4 (min(min(k0,k1),min(k2,k3)))

#define MERGELOOP { \
    unsigned long long mask = __ballot(mk < tau); \
    while (mask) { \
        int srcl = (int)__ffsll((long long)mask) - 1; \
        unsigned long long kk = __shfl(mk, srcl, 64); \
        unsigned long long below = __ballot(list < kk) & 0xFFFFull; \
        int pos = __popcll(below); \
        unsigned long long sh = __shfl_up(list, 1, 64); \
        if (lane == pos)                  list = kk; \
        else if (lane > pos && lane < K_) list = sh; \
        tau = __shfl(list, K_ - 1, 64); \
        if (lane == srcl) { \
            if      (k0 == mk) k0 = ~0ULL; \
            else if (k1 == mk) k1 = ~0ULL; \
            else if (k2 == mk) k2 = ~0ULL; \
            else               k3 = ~0ULL; \
            mk = MIN4; \
        } \
        mask = __ballot(mk < tau); \
    } \
    taud = __uint_as_float((unsigned)(tau >> 32)); }

    {   // iter 0: bitonic warm-up over first 64 k0-candidates
        float4 px = bx4[lane], py = by4[lane], pz = bz4[lane];
        float d0 = DIST(px.x,py.x,pz.x);
        float d1 = DIST(px.y,py.y,pz.y);
        float d2 = DIST(px.z,py.z,pz.z);
        float d3 = DIST(px.w,py.w,pz.w);
        unsigned long long j0 = (unsigned)(lane*4);
        unsigned long long k0 = ((unsigned long long)__float_as_uint(d0) << 32) | (j0+0);
        unsigned long long k1 = ((unsigned long long)__float_as_uint(d1) << 32) | (j0+1);
        unsigned long long k2 = ((unsigned long long)__float_as_uint(d2) << 32) | (j0+2);
        unsigned long long k3 = ((unsigned long long)__float_as_uint(d3) << 32) | (j0+3);
        unsigned long long key = k0;
#pragma unroll
        for (int k = 2; k <= 64; k <<= 1) {
#pragma unroll
            for (int j = k >> 1; j > 0; j >>= 1) {
                unsigned long long o = __shfl_xor(key, j, 64);
                bool up  = ((lane & k) == 0);
                bool low = ((lane & j) == 0);
                bool keepmin = (low == up);
                unsigned long long mn = (o < key) ? o : key;
                unsigned long long mx = (o < key) ? key : o;
                key = keepmin ? mn : mx;
            }
        }
        if (lane < K_) list = key;
        tau  = __shfl(list, K_ - 1, 64);
        taud = __uint_as_float((unsigned)(tau >> 32));
        k0 = ~0ULL;
        unsigned long long mk = MIN4;
        MERGELOOP
    }

    for (int i = 1; i < M_/256; ++i) {
        float4 px = bx4[i*64 + lane];
        float4 py = by4[i*64 + lane];
        float4 pz = bz4[i*64 + lane];
        float d0 = DIST(px.x,py.x,pz.x);
        float d1 = DIST(px.y,py.y,pz.y);
        float d2 = DIST(px.z,py.z,pz.z);
        float d3 = DIST(px.w,py.w,pz.w);
        bool any = (d0 <= taud) | (d1 <= taud) | (d2 <= taud) | (d3 <= taud);
        if (__ballot(any)) {
            unsigned long long j0 = (unsigned)(i*256 + lane*4);
            unsigned long long k0 = ((unsigned long long)__float_as_uint(d0) << 32) | (j0+0);
            unsigned long long k1 = ((unsigned long long)__float_as_uint(d1) << 32) | (j0+1);
            unsigned long long k2 = ((unsigned long long)__float_as_uint(d2) << 32) | (j0+2);
            unsigned long long k3 = ((unsigned long long)__float_as_uint(d3) << 32) | (j0+3);
            unsigned long long mk = MIN4;
            MERGELOOP
        }
    }
#undef MERGELOOP
#undef MIN4
#undef DIST
    if (lane < K_)
        out_knn[(size_t)q*K_ + lane] = (int)(unsigned)list;
}

// --- k_f role ---
__device__ void f_body(const float* __restrict__ feature, const float* __restrict__ w,
                       const float* __restrict__ g, const float* __restrict__ bb,
                       float* __restrict__ f_t, int m0, int t, char* smem)
{
    float4* As4 = (float4*)smem;
    float4* Bs4 = (float4*)(smem + 32 * LDSA * 16);
    int tm = t >> 4, tn = t & 15;
    int b = m0 >> 11;
    size_t col0_4 = (size_t)(m0 & (N_ - 1)) >> 2;
    const float4* src4 = (const float4*)feature + (size_t)b * C1_ * (N_ / 4);
    float acc[4][8] = {};
    for (int k0 = 0; k0 < C1_; k0 += 32) {
        stage_direct64(As4, src4, N_ / 4, k0, col0_4, t);
        stage_transposeB((float*)Bs4, w, C1_, k0, t);
        __syncthreads();
        gemm_step64(As4, Bs4, tm, tn, acc);
        __syncthreads();
    }
    int c0 = tn * 8;
    float gc[8], bc[8];
    load8(g + c0, gc); load8(bb + c0, bc);
#pragma unroll
    for (int mm = 0; mm < 4; ++mm) {
        int m = m0 + tm * 4 + mm;
        float o[8];
#pragma unroll
        for (int j = 0; j < 8; ++j)
            o[j] = fmaxf(fmaf(acc[mm][j], gc[j] * BNINV, bc[j]), 0.f);
        store8(f_t + (size_t)m * C_ + c0, o);
    }
}

// --- three_nn role (wave/query) ---
__device__ void tnn_body(const float* __restrict__ xyz, const float* __restrict__ txyz,
                         int* __restrict__ idx3, float* __restrict__ w3,
                         int q, int lane)
{
    int b = q / M_;
    const float* src = xyz + (size_t)b * N_ * 3;
    float qx = txyz[(size_t)q*3+0], qy = txyz[(size_t)q*3+1], qz = txyz[(size_t)q*3+2];

    unsigned long long p0 = ~0ULL, p1 = ~0ULL, p2 = ~0ULL;
    for (int i = 0; i < N_/64; ++i) {
        int j = lane + (i << 6);
        float dx = src[j*3+0]-qx, dy = src[j*3+1]-qy, dz = src[j*3+2]-qz;
        float d = __fadd_rn(__fadd_rn(__fmul_rn(dx,dx), __fmul_rn(dy,dy)), __fmul_rn(dz,dz));
        unsigned long long key = ((unsigned long long)__float_as_uint(d) << 32) | (unsigned)j;
        if (key < p2) {
            p2 = key;
            if (p2 < p1) { unsigned long long t = p1; p1 = p2; p2 = t; }
            if (p1 < p0) { unsigned long long t = p0; p0 = p1; p1 = t; }
        }
    }
    unsigned long long wmin[3];
    unsigned long long h = p0;
#pragma unroll
    for (int r = 0; r < 3; ++r) {
        unsigned long long w = h;
#pragma unroll
        for (int s = 1; s < 64; s <<= 1) {
            unsigned long long o = __shfl_xor(w, s, 64);
            w = (o < w) ? o : w;
        }
        wmin[r] = w;
        if (h == w) { p0 = p1; p1 = p2; p2 = ~0ULL; h = p0; }
    }
    if (lane == 0) {
        float d0 = __uint_as_float((unsigned)(wmin[0] >> 32));
        float d1 = __uint_as_float((unsigned)(wmin[1] >> 32));
        float d2 = __uint_as_float((unsigned)(wmin[2] >> 32));
        float s0 = sqrtf(fmaxf(d0, 0.f)), s1 = sqrtf(fmaxf(d1, 0.f)), s2 = sqrtf(fmaxf(d2, 0.f));
        float r0 = 1.f/(s0+1e-8f), r1 = 1.f/(s1+1e-8f), r2 = 1.f/(s2+1e-8f);
        float inv = 1.f/(r0+r1+r2);
        idx3[(size_t)q*3+0] = (int)(unsigned)wmin[0];
        idx3[(size_t)q*3+1] = (int)(unsigned)wmin[1];
        idx3[(size_t)q*3+2] = (int)(unsigned)wmin[2];
        w3[(size_t)q*3+0] = r0*inv; w3[(size_t)q*3+1] = r1*inv; w3[(size_t)q*3+2] = r2*inv;
    }
}

// --- k_feat role ---
__device__ void feat_body(const float* __restrict__ tfeat, const float* __restrict__ w2,
                          const float* __restrict__ g, const float* __restrict__ bb,
                          const float* __restrict__ f_t, const int* __restrict__ idx3,
                          const float* __restrict__ w3, float* __restrict__ x,
                          int m0, int t, char* smem)
{
    float4* As4 = (float4*)smem;
    float4* Bs4 = (float4*)(smem + 32 * LDSA * 16);
    int tm = t >> 4, tn = t & 15;
    int b = m0 >> 13;
    size_t col0_4 = (size_t)(m0 & (M_ - 1)) >> 2;
    const float4* src4 = (const float4*)tfeat + (size_t)b * C_ * (M_ / 4);
    float acc[4][8] = {};
    for (int k0 = 0; k0 < C_; k0 += 32) {
        stage_direct64(As4, src4, M_ / 4, k0, col0_4, t);
        stage_transposeB((float*)Bs4, w2, C_, k0, t);
        __syncthreads();
        gemm_step64(As4, Bs4, tm, tn, acc);
        __syncthreads();
    }
    int c0 = tn * 8;
    float gc[8], bc[8];
    load8(g + c0, gc); load8(bb + c0, bc);
    const float* fb = f_t + (size_t)b * N_ * C_;
#pragma unroll
    for (int mm = 0; mm < 4; ++mm) {
        int m = m0 + tm * 4 + mm;
        int   i0 = idx3[m*3+0], i1 = idx3[m*3+1], i2 = idx3[m*3+2];
        float u0 = w3[m*3+0],  u1 = w3[m*3+1],  u2 = w3[m*3+2];
        float r0[8], r1[8], r2[8];
        load8(fb + (size_t)i0 * C_ + c0, r0);
        load8(fb + (size_t)i1 * C_ + c0, r1);
        load8(fb + (size_t)i2 * C_ + c0, r2);
        float o[8];
#pragma unroll
        for (int j = 0; j < 8; ++j) {
            float y = fmaxf(fmaf(acc[mm][j], gc[j] * BNINV, bc[j]), 0.f);
            o[j] = y + u0 * r0[j] + u1 * r1[j] + u2 * r2[j];
        }
        store8(x + (size_t)m * C_ + c0, o);
    }
}

// --- lqkv role: x1 in LDS (transposed) then q/k/v GEMMs ---
__device__ void lqkv_body(const float* __restrict__ xin,
                          const float* __restrict__ w1, const float* __restrict__ g1,
                          const float* __restrict__ b1,
                          const float* __restrict__ wq, const float* __restrict__ bq,
                          const float* __restrict__ wk, const float* __restrict__ bk,
                          const float* __restrict__ wv, const float* __restrict__ bv,
                          float* __restrict__ q, float* __restrict__ k, float* __restrict__ v,
                          int m0, int t, char* smem)
{
    float*  Asf = (float*)smem;
    float4* Bs4 = (float4*)(smem + 128 * 68 * 4);
    int tm = t >> 4, tn = t & 15;
    int c0 = tn * 8;

    for (int k0 = 0; k0 < C_; k0 += 32)
        stage_transposeA(Asf + k0 * 68, xin, m0, C_, k0, t);

    float acc[4][8] = {};
    for (int k0 = 0; k0 < C_; k0 += 32) {
        stage_transposeB((float*)Bs4, w1, C_, k0, t);
        __syncthreads();
        gemm_step64((const float4*)Asf + k0 * 17, Bs4, tm, tn, acc);
        __syncthreads();
    }
    {
        float gc[8], bc[8];
        load8(g1 + c0, gc); load8(b1 + c0, bc);
#pragma unroll
        for (int mm = 0; mm < 4; ++mm) {
            int ml = tm * 4 + mm;
#pragma unroll
            for (int j = 0; j < 8; ++j)
                Asf[(c0 + j) * 68 + ml] = fmaxf(fmaf(acc[mm][j], gc[j] * BNINV, bc[j]), 0.f);
        }
    }
    __syncthreads();

#pragma unroll 1
    for (int which = 0; which < 3; ++which) {
        const float* W  = (which == 0) ? wq : (which == 1) ? wk : wv;
        const float* bi = (which == 0) ? bq : (which == 1) ? bk : bv;
        float*       out= (which == 0) ? q  : (which == 1) ? k  : v;
        float acc2[4][8] = {};
        for (int k0 = 0; k0 < C_; k0 += 32) {
            stage_transposeB((float*)Bs4, W, C_, k0, t);
            __syncthreads();
            gemm_step64((const float4*)Asf + k0 * 17, Bs4, tm, tn, acc2);
            __syncthreads();
        }
        float bc[8];
        load8(bi + c0, bc);
#pragma unroll
        for (int mm = 0; mm < 4; ++mm) {
            int m = m0 + tm * 4 + mm;
            float o[8];
#pragma unroll
            for (int j = 0; j < 8; ++j) o[j] = acc2[mm][j] + bc[j];
            store8(out + (size_t)m * C_ + c0, o);
        }
    }
}

// ============================ kernels ======================================

extern "C" __global__ __launch_bounds__(256) void k_soa(
    const float* __restrict__ txyz,
    float* __restrict__ cx, float* __restrict__ cy, float* __restrict__ cz)
{
    int t = blockIdx.x * 256 + threadIdx.x;
    if (t < B_ * M_) {
        cx[t] = txyz[t*3+0];
        cy[t] = txyz[t*3+1];
        cz[t] = txyz[t*3+2];
    }
}

// FAT1: kNN[0:KNN1) + k_f + three_nn
extern "C" __global__ __launch_bounds__(256) void k_fat1(
    const float* __restrict__ cx, const float* __restrict__ cy,
    const float* __restrict__ cz, int* __restrict__ out_knn,
    const float* __restrict__ feature, const float* __restrict__ w,
    const float* __restrict__ g, const float* __restrict__ bb,
    float* __restrict__ f_t,
    const float* __restrict__ xyz, const float* __restrict__ txyz,
    int* __restrict__ idx3, float* __restrict__ w3)
{
    __shared__ __align__(16) char smem[32 * LDSA * 16 + 32 * LDSB * 16];
    int bid = blockIdx.x, tid = threadIdx.x;
    if (bid < KNN1)
        knn_body(cx, cy, cz, out_knn, bid, tid);
    else if (bid < KNN1 + FB)
        f_body(feature, w, g, bb, f_t, (bid - KNN1) * 64, tid, smem);
    else
        tnn_body(xyz, txyz, idx3, w3, (bid - KNN1 - FB) * 4 + (tid >> 6), tid & 63);
}

// FAT2: kNN[KNN1:KNN1+KNN2) + k_feat
extern "C" __global__ __launch_bounds__(256) void k_fat2(
    const float* __restrict__ cx, const float* __restrict__ cy,
    const float* __restrict__ cz, int* __restrict__ out_knn,
    const float* __restrict__ tfeat, const float* __restrict__ w2,
    const float* __restrict__ g, const float* __restrict__ bb,
    const float* __restrict__ f_t, const int* __restrict__ idx3,
    const float* __restrict__ w3, float* __restrict__ x)
{
    __shared__ __align__(16) char smem[32 * LDSA * 16 + 32 * LDSB * 16];
    int bid = blockIdx.x, tid = threadIdx.x;
    if (bid < KNN2)
        knn_body(cx, cy, cz, out_knn, KNN1 + bid, tid);
    else
        feat_body(tfeat, w2, g, bb, f_t, idx3, w3, x, (bid - KNN2) * 64, tid, smem);
}

// FAT3: kNN[KNN1+KNN2:4096) + lqkv
extern "C" __global__ __launch_bounds__(256) void k_fat3(
    const float* __restrict__ cx, const float* __restrict__ cy,
    const float* __restrict__ cz, int* __restrict__ out_knn,
    const float* __restrict__ xin,
    const float* __restrict__ w1, const float* __restrict__ g1, const float* __restrict__ b1,
    const float* __restrict__ wq, const float* __restrict__ bq,
    const float* __restrict__ wk, const float* __restrict__ bk,
    const float* __restrict__ wv, const float* __restrict__ bv,
    float* __restrict__ q, float* __restrict__ k, float* __restrict__ v)
{
    __shared__ __align__(16) char smem[128 * 68 * 4 + 32 * LDSB * 16];
    int bid = blockIdx.x, tid = threadIdx.x;
    if (bid < KNN3)
        knn_body(cx, cy, cz, out_knn, KNN1 + KNN2 + bid, tid);
    else
        lqkv_body(xin, w1, g1, b1, wq, bq, wk, bk, wv, bv, q, k, v,
                  (bid - KNN3) * 64, tid, smem);
}

// ---------------------------------------------------------------------------
// Attention core: batched gathers, pr MLP + w MLP + softmax + agg + bn2.
extern "C" __global__ __launch_bounds__(128) void k_attn2(
    const float* __restrict__ q, const float* __restrict__ kf, const float* __restrict__ vf,
    const int* __restrict__ knn, const float* __restrict__ txyz,
    const float* __restrict__ p1w, const float* __restrict__ p1b,
    const float* __restrict__ pbg, const float* __restrict__ pbb,
    const float* __restrict__ p2w, const float* __restrict__ p2b,
    const float* __restrict__ wb1g, const float* __restrict__ wb1b,
    const float* __restrict__ wl1, const float* __restrict__ wl1b,
    const float* __restrict__ wb2g, const float* __restrict__ wb2b,
    const float* __restrict__ wl2, const float* __restrict__ wl2b,
    const float* __restrict__ bn2g, const float* __restrict__ bn2b,
    float* __restrict__ x2out)
{
    __shared__ int   nbs[K_];
    __shared__ float scrd[K_][3];
    __shared__ float tshs[K_ * C_];
    __shared__ float svs [K_ * C_];
    __shared__ float wl1s[CS_ * 132];
    __shared__ float wl2s[CS_ * 17];
    __shared__ float ashs[K_ * 17];
    __shared__ float wshs[K_ * 17];

    int bm = blockIdx.x;
    int b  = bm >> 13;
    int c  = threadIdx.x;

#pragma unroll
    for (int i = 0; i < 16; ++i) {
        int idx = c + i * 128;
        wl1s[(idx >> 7) * 132 + (idx & 127)] = wl1[idx];
    }
    {
        int i1 = c, i2 = c + 128;
        if (i1 < 256) wl2s[(i1 >> 4) * 17 + (i1 & 15)] = wl2[i1];
        if (i2 < 256) wl2s[(i2 >> 4) * 17 + (i2 & 15)] = wl2[i2];
    }
    if (c < K_) nbs[c] = knn[(size_t)bm * K_ + c];
    __syncthreads();

    float kfv[K_], vfv[K_];
    const float* txb = txyz + (size_t)b * M_ * 3;
#pragma unroll
    for (int t = 0; t < K_; ++t) {
        size_t nrow = ((size_t)b * M_ + nbs[t]) * C_ + c;
        kfv[t] = kf[nrow];
        vfv[t] = vf[nrow];
    }
    if (c < 48) {
        int t = c / 3, comp = c - t * 3;
        scrd[t][comp] = txb[nbs[t] * 3 + comp];
    }

    float qc = q[(size_t)bm * C_ + c];
    float qx = txyz[(size_t)bm*3+0], qy = txyz[(size_t)bm*3+1], qz = txyz[(size_t)bm*3+2];
    float p2w0 = p2w[c*3+0], p2w1 = p2w[c*3+1], p2w2 = p2w[c*3+2], p2bc = p2b[c];
    float b1s = wb1g[c]*BNINV, b1b = wb1b[c];
    float a00=p1w[0],a01=p1w[1],a02=p1w[2],a10=p1w[3],a11=p1w[4],a12=p1w[5],a20=p1w[6],a21=p1w[7],a22=p1w[8];
    float pb0=p1b[0], pb1=p1b[1], pb2=p1b[2];
    float g0=pbg[0]*BNINV, g1=pbg[1]*BNINV, g2=pbg[2]*BNINV;
    float hb0=pbb[0], hb1=pbb[1], hb2=pbb[2];
    __syncthreads();

#pragma unroll
    for (int t = 0; t < K_; ++t) {
        float dx = scrd[t][0]-qx, dy = scrd[t][1]-qy, dz = scrd[t][2]-qz;
        float h0 = fmaxf(fmaf(fmaf(a02,dz, fmaf(a01,dy, fmaf(a00,dx, pb0))), g0, hb0), 0.f);
        float h1 = fmaxf(fmaf(fmaf(a12,dz, fmaf(a11,dy, fmaf(a10,dx, pb1))), g1, hb1), 0.f);
        float h2 = fmaxf(fmaf(fmaf(a22,dz, fmaf(a21,dy, fmaf(a20,dx, pb2))), g2, hb2), 0.f);
        float pr = fmaf(p2w2,h2, fmaf(p2w1,h1, fmaf(p2w0,h0, p2bc)));
        float r = kfv[t] - qc + pr;
        tshs[t*C_ + c] = fmaxf(fmaf(r, b1s, b1b), 0.f);
        svs [t*C_ + c] = vfv[t] + pr;
    }
    __syncthreads();

    {
        int s = c >> 3, u = c & 7;
        float w1b = wl1b[s], gg = wb2g[s]*BNINV, gb = wb2b[s];
        for (int nb = 0; nb < K_; ++nb) {
            float a = 0.f;
#pragma unroll
            for (int i = 0; i < 16; ++i)
                a = fmaf(wl1s[s*132 + u + 8*i], tshs[nb*C_ + u + 8*i], a);
            a += __shfl_down(a, 4, 8);
            a += __shfl_down(a, 2, 8);
            a += __shfl_down(a, 1, 8);
            if (u == 0)
                ashs[nb*17 + s] = fmaxf(fmaf(a + w1b, gg, gb), 0.f);
        }
    }
    __syncthreads();

    {
        int nb = c >> 3;
        int cs1 = c & 7, cs2 = (c & 7) + 8;
        float a1 = wl2b[cs1], a2 = wl2b[cs2];
#pragma unroll
        for (int j = 0; j < CS_; ++j) {
            float av = ashs[nb*17 + j];
            a1 = fmaf(wl2s[cs1*17 + j], av, a1);
            a2 = fmaf(wl2s[cs2*17 + j], av, a2);
        }
        wshs[nb*17 + cs1] = a1;
        wshs[nb*17 + cs2] = a2;
    }
    __syncthreads();

    if (c < CS_) {
        float mx = -3e38f;
#pragma unroll
        for (int nb = 0; nb < K_; ++nb) mx = fmaxf(mx, wshs[nb*17 + c]);
        float ssum = 0.f;
#pragma unroll
        for (int nb = 0; nb < K_; ++nb) {
            float e = __expf(wshs[nb*17 + c] - mx);
            wshs[nb*17 + c] = e; ssum += e;
        }
        float inv = 1.f / ssum;
#pragma unroll
        for (int nb = 0; nb < K_; ++nb) wshs[nb*17 + c] *= inv;
    }
    __syncthreads();

    float agg = 0.f;
    int cs = c & (CS_ - 1);
#pragma unroll
    for (int nb = 0; nb < K_; ++nb)
        agg = fmaf(svs[nb*C_ + c], wshs[nb*17 + cs], agg);
    float x2 = fmaxf(fmaf(agg, bn2g[c]*BNINV, bn2b[c]), 0.f);
    x2out[(size_t)bm * C_ + c] = x2;
}

// ---------------------------------------------------------------------------
// out[b][c][m] = relu(bn3(x2 @ l3w.T) + identity)   (transposed store)
extern "C" __global__ __launch_bounds__(256) void k_lin3(
    const float* __restrict__ x2, const float* __restrict__ w,
    const float* __restrict__ g, const float* __restrict__ bb,
    const float* __restrict__ xid, float* __restrict__ out)
{
    __shared__ float4 As4[32 * LDSA], Bs4[32 * LDSB];
    int t = threadIdx.x, tm = t >> 4, tn = t & 15;
    int m0 = blockIdx.x * 64;
    int b  = m0 >> 13;
    float acc[4][8] = {};
    for (int k0 = 0; k0 < C_; k0 += 32) {
        stage_transposeA((float*)As4, x2, m0, C_, k0, t);
        stage_transposeB((float*)Bs4, w, C_, k0, t);
        __syncthreads();
        gemm_step64(As4, Bs4, tm, tn, acc);
        __syncthreads();
    }
    int c0 = tn * 8;
    float gc[8], bc[8];
    load8(g + c0, gc); load8(bb + c0, bc);
#pragma unroll
    for (int mm = 0; mm < 4; ++mm) {
        int m = m0 + tm * 4 + mm;
        float idv[8];
        load8(xid + (size_t)m * C_ + c0, idv);
#pragma unroll
        for (int j = 0; j < 8; ++j) {
            float x3 = fmaf(acc[mm][j], gc[j] * BNINV, bc[j]);
            acc[mm][j] = fmaxf(x3 + idv[j], 0.f);
        }
    }
    int mloc = (m0 & (M_ - 1)) + tm * 4;
    float* ob = out + (size_t)b * C_ * M_;
#pragma unroll
    for (int j = 0; j < 8; ++j) {
        float* p = ob + (size_t)(c0 + j) * M_ + mloc;
        *(float4*)p = make_float4(acc[0][j], acc[1][j], acc[2][j], acc[3][j]);
    }
}

// ---------------------------------------------------------------------------
extern "C" void kernel_launch(void* const* d_in, const int* in_sizes, int n_in,
                              void* d_out, int out_size, void* d_ws, size_t ws_size,
                              hipStream_t stream)
{
    const float* xyz   = (const float*)d_in[0];
    const float* feat  = (const float*)d_in[1];
    const float* txyz  = (const float*)d_in[2];
    const float* tfeat = (const float*)d_in[3];
    const float* tu1w  = (const float*)d_in[4];
    const float* tu1g  = (const float*)d_in[5];
    const float* tu1b  = (const float*)d_in[6];
    const float* tu2w  = (const float*)d_in[7];
    const float* tu2g  = (const float*)d_in[8];
    const float* tu2b  = (const float*)d_in[9];
    const float* bl1w  = (const float*)d_in[10];
    const float* bl1g  = (const float*)d_in[11];
    const float* bl1b  = (const float*)d_in[12];
    const float* wq    = (const float*)d_in[13];
    const float* bq    = (const float*)d_in[14];
    const float* wk    = (const float*)d_in[15];
    const float* bk    = (const float*)d_in[16];
    const float* wv    = (const float*)d_in[17];
    const float* bv    = (const float*)d_in[18];
    const float* p1w   = (const float*)d_in[19];
    const float* p1b   = (const float*)d_in[20];
    const float* pbg   = (const float*)d_in[21];
    const float* pbb   = (const float*)d_in[22];
    const float* p2w   = (const float*)d_in[23];
    const float* p2b   = (const float*)d_in[24];
    const float* wb1g  = (const float*)d_in[25];
    const float* wb1b  = (const float*)d_in[26];
    const float* wl1   = (const float*)d_in[27];
    const float* wl1b  = (const float*)d_in[28];
    const float* wb2g  = (const float*)d_in[29];
    const float* wb2b  = (const float*)d_in[30];
    const float* wl2   = (const float*)d_in[31];
    const float* wl2b  = (const float*)d_in[32];
    const float* bn2g  = (const float*)d_in[33];
    const float* bn2b  = (const float*)d_in[34];
    const float* l3w   = (const float*)d_in[35];
    const float* bn3g  = (const float*)d_in[36];
    const float* bn3b  = (const float*)d_in[37];

    char* ws = (char*)d_ws;
    size_t off = 0;
    auto alloc = [&](size_t bytes) { void* p = ws + off; off += (bytes + 255) & ~(size_t)255; return p; };
    float* f_t  = (float*)alloc(sizeof(float) * B_ * N_ * C_);
    int*   idx3 = (int*)  alloc(sizeof(int)   * B_ * M_ * 3);
    float* w3   = (float*)alloc(sizeof(float) * B_ * M_ * 3);
    float* x    = (float*)alloc(sizeof(float) * B_ * M_ * C_);
    float* x2   = (float*)alloc(sizeof(float) * B_ * M_ * C_);
    float* qb   = (float*)alloc(sizeof(float) * B_ * M_ * C_);
    float* kb   = (float*)alloc(sizeof(float) * B_ * M_ * C_);
    float* vb   = (float*)alloc(sizeof(float) * B_ * M_ * C_);
    int*   knn  = (int*)  alloc(sizeof(int)   * B_ * M_ * K_);
    float* cx   = (float*)alloc(sizeof(float) * B_ * M_);
    float* cy   = (float*)alloc(sizeof(float) * B_ * M_);
    float* cz   = (float*)alloc(sizeof(float) * B_ * M_);

    k_soa  <<<(B_*M_+255)/256,     256, 0, stream>>>(txyz, cx, cy, cz);
    k_fat1 <<<KNN1 + FB + TNNB,    256, 0, stream>>>(cx, cy, cz, knn,
                                                     feat, tu1w, tu1g, tu1b, f_t,
                                                     xyz, txyz, idx3, w3);
    k_fat2 <<<KNN2 + FEATB,        256, 0, stream>>>(cx, cy, cz, knn,
                                                     tfeat, tu2w, tu2g, tu2b,
                                                     f_t, idx3, w3, x);
    k_fat3 <<<KNN3 + LQKVB,        256, 0, stream>>>(cx, cy, cz, knn,
                                                     x, bl1w, bl1g, bl1b,
                                                     wq, bq, wk, bk, wv, bv, qb, kb, vb);
    k_attn2<<<B_*M_,               128, 0, stream>>>(qb, kb, vb, knn, txyz,
                                                     p1w, p1b, pbg, pbb, p2w, p2b,
                                                     wb1g, wb1b, wl1, wl1b, wb2g, wb2b, wl2, wl2b,
                                                     bn2g, bn2b, x2);
    k_lin3 <<<B_*M_/64,            256, 0, stream>>>(x2, l3w, bn3g, bn3b, x, (float*)d_out);
}

// Round 18
// 395.454 us; speedup vs baseline: 1.0815x; 1.0815x over previous
//
#include <hip/hip_runtime.h>
#include <cstddef>
#include <cstdint>

#define B_  2
#define N_  2048
#define M_  8192
#define C1_ 256
#define C_  128
#define K_  16
#define CS_ 16

// 1/sqrt(1+1e-5)
#define BNINV 0.9999950000374997f

// ======================= tiled fp32 GEMM machinery =========================
// BM=64, BN=128, BK=32, 256 threads, 4x8 micro-tile per thread.
#define LDSA 17   // float4 stride of A k-row (64 f + 4 pad)
#define LDSB 33   // float4 stride of B k-row (128 f + 4 pad)

__device__ __forceinline__ void stage_direct64(float4* Ls4, const float4* src4,
                                               size_t row_stride4, int k0,
                                               size_t col0_4, int t)
{
#pragma unroll
    for (int i = 0; i < 2; ++i) {
        int idx = t + i * 256;
        int kk = idx >> 4, f4 = idx & 15;
        Ls4[kk * LDSA + f4] = src4[(size_t)(k0 + kk) * row_stride4 + col0_4 + f4];
    }
}

__device__ __forceinline__ void stage_transposeA(float* Lsf, const float* src,
                                                 int row0, int ldk, int k0, int t)
{
    int u = t & 7, r = t >> 3;
#pragma unroll
    for (int i = 0; i < 2; ++i) {
        int row = r + i * 32;
        float4 v = *(const float4*)(src + (size_t)(row0 + row) * ldk + k0 + u * 4);
        Lsf[(u * 4 + 0) * 68 + row] = v.x;
        Lsf[(u * 4 + 1) * 68 + row] = v.y;
        Lsf[(u * 4 + 2) * 68 + row] = v.z;
        Lsf[(u * 4 + 3) * 68 + row] = v.w;
    }
}

__device__ __forceinline__ void stage_transposeB(float* Lsf, const float* src,
                                                 int ldk, int k0, int t)
{
    int u = t & 7, r = t >> 3;
#pragma unroll
    for (int i = 0; i < 4; ++i) {
        int row = r + i * 32;
        float4 v = *(const float4*)(src + (size_t)row * ldk + k0 + u * 4);
        Lsf[(u * 4 + 0) * 132 + row] = v.x;
        Lsf[(u * 4 + 1) * 132 + row] = v.y;
        Lsf[(u * 4 + 2) * 132 + row] = v.z;
        Lsf[(u * 4 + 3) * 132 + row] = v.w;
    }
}

__device__ __forceinline__ void gemm_step64(const float4* As4, const float4* Bs4,
                                            int tm, int tn, float acc[4][8])
{
#pragma unroll 4
    for (int kk = 0; kk < 32; ++kk) {
        float4 a0 = As4[kk * LDSA + tm];
        float4 b0 = Bs4[kk * LDSB + tn * 2];
        float4 b1 = Bs4[kk * LDSB + tn * 2 + 1];
        float av[4] = {a0.x,a0.y,a0.z,a0.w};
        float bv[8] = {b0.x,b0.y,b0.z,b0.w,b1.x,b1.y,b1.z,b1.w};
#pragma unroll
        for (int i = 0; i < 4; ++i)
#pragma unroll
            for (int j = 0; j < 8; ++j)
                acc[i][j] = fmaf(av[i], bv[j], acc[i][j]);
    }
}

__device__ __forceinline__ void load8(const float* p, float* v)
{
    float4 a = *(const float4*)p, b = *(const float4*)(p + 4);
    v[0]=a.x; v[1]=a.y; v[2]=a.z; v[3]=a.w; v[4]=b.x; v[5]=b.y; v[6]=b.z; v[7]=b.w;
}
__device__ __forceinline__ void store8(float* p, const float* v)
{
    *(float4*)p       = make_float4(v[0],v[1],v[2],v[3]);
    *(float4*)(p + 4) = make_float4(v[4],v[5],v[6],v[7]);
}

// ---------------------------------------------------------------------------
// f_t[bn][c] = relu(bn1(sum_j W1[c][j] * F[b][j][n]))   (A direct, K=256)
extern "C" __global__ __launch_bounds__(256) void k_f(
    const float* __restrict__ feature, const float* __restrict__ w,
    const float* __restrict__ g, const float* __restrict__ bb,
    float* __restrict__ f_t)
{
    __shared__ float4 As4[32 * LDSA], Bs4[32 * LDSB];
    int t = threadIdx.x, tm = t >> 4, tn = t & 15;
    int m0 = blockIdx.x * 64;
    int b = m0 >> 11;
    size_t col0_4 = (size_t)(m0 & (N_ - 1)) >> 2;
    const float4* src4 = (const float4*)feature + (size_t)b * C1_ * (N_ / 4);
    float acc[4][8] = {};
    for (int k0 = 0; k0 < C1_; k0 += 32) {
        stage_direct64(As4, src4, N_ / 4, k0, col0_4, t);
        stage_transposeB((float*)Bs4, w, C1_, k0, t);
        __syncthreads();
        gemm_step64(As4, Bs4, tm, tn, acc);
        __syncthreads();
    }
    int c0 = tn * 8;
    float gc[8], bc[8];
    load8(g + c0, gc); load8(bb + c0, bc);
#pragma unroll
    for (int mm = 0; mm < 4; ++mm) {
        int m = m0 + tm * 4 + mm;
        float o[8];
#pragma unroll
        for (int j = 0; j < 8; ++j)
            o[j] = fmaxf(fmaf(acc[mm][j], gc[j] * BNINV, bc[j]), 0.f);
        store8(f_t + (size_t)m * C_ + c0, o);
    }
}

// ---------------------------------------------------------------------------
// SoA transpose of target_xyz
extern "C" __global__ __launch_bounds__(256) void k_soa(
    const float* __restrict__ txyz,
    float* __restrict__ cx, float* __restrict__ cy, float* __restrict__ cz)
{
    int t = blockIdx.x * 256 + threadIdx.x;
    if (t < B_ * M_) {
        cx[t] = txyz[t*3+0];
        cy[t] = txyz[t*3+1];
        cz[t] = txyz[t*3+2];
    }
}

// ---------------------------------------------------------------------------
// three_nn (wave/query, packed u64 keys)
extern "C" __global__ __launch_bounds__(256) void k_three_nn(
    const float* __restrict__ xyz, const float* __restrict__ txyz,
    int* __restrict__ idx3, float* __restrict__ w3)
{
    int q    = blockIdx.x * 4 + (threadIdx.x >> 6);
    int lane = threadIdx.x & 63;
    int b    = q / M_;
    const float* src = xyz + (size_t)b * N_ * 3;
    float qx = txyz[(size_t)q*3+0], qy = txyz[(size_t)q*3+1], qz = txyz[(size_t)q*3+2];

    unsigned long long p0 = ~0ULL, p1 = ~0ULL, p2 = ~0ULL;
    for (int i = 0; i < N_/64; ++i) {
        int j = lane + (i << 6);
        float dx = src[j*3+0]-qx, dy = src[j*3+1]-qy, dz = src[j*3+2]-qz;
        float d = __fadd_rn(__fadd_rn(__fmul_rn(dx,dx), __fmul_rn(dy,dy)), __fmul_rn(dz,dz));
        unsigned long long key = ((unsigned long long)__float_as_uint(d) << 32) | (unsigned)j;
        if (key < p2) {
            p2 = key;
            if (p2 < p1) { unsigned long long t = p1; p1 = p2; p2 = t; }
            if (p1 < p0) { unsigned long long t = p0; p0 = p1; p1 = t; }
        }
    }
    unsigned long long wmin[3];
    unsigned long long h = p0;
#pragma unroll
    for (int r = 0; r < 3; ++r) {
        unsigned long long w = h;
#pragma unroll
        for (int s = 1; s < 64; s <<= 1) {
            unsigned long long o = __shfl_xor(w, s, 64);
            w = (o < w) ? o : w;
        }
        wmin[r] = w;
        if (h == w) { p0 = p1; p1 = p2; p2 = ~0ULL; h = p0; }
    }
    if (lane == 0) {
        float d0 = __uint_as_float((unsigned)(wmin[0] >> 32));
        float d1 = __uint_as_float((unsigned)(wmin[1] >> 32));
        float d2 = __uint_as_float((unsigned)(wmin[2] >> 32));
        float s0 = sqrtf(fmaxf(d0, 0.f)), s1 = sqrtf(fmaxf(d1, 0.f)), s2 = sqrtf(fmaxf(d2, 0.f));
        float r0 = 1.f/(s0+1e-8f), r1 = 1.f/(s1+1e-8f), r2 = 1.f/(s2+1e-8f);
        float inv = 1.f/(r0+r1+r2);
        idx3[(size_t)q*3+0] = (int)(unsigned)wmin[0];
        idx3[(size_t)q*3+1] = (int)(unsigned)wmin[1];
        idx3[(size_t)q*3+2] = (int)(unsigned)wmin[2];
        w3[(size_t)q*3+0] = r0*inv; w3[(size_t)q*3+1] = r1*inv; w3[(size_t)q*3+2] = r2*inv;
    }
}

// ---------------------------------------------------------------------------
// x[m][c] = relu(bn2(tu_lin2_w @ target_feature)) + three_interpolate(f_t)
extern "C" __global__ __launch_bounds__(256) void k_feat(
    const float* __restrict__ tfeat, const float* __restrict__ w2,
    const float* __restrict__ g, const float* __restrict__ bb,
    const float* __restrict__ f_t, const int* __restrict__ idx3,
    const float* __restrict__ w3, float* __restrict__ x)
{
    __shared__ float4 As4[32 * LDSA], Bs4[32 * LDSB];
    int t = threadIdx.x, tm = t >> 4, tn = t & 15;
    int m0 = blockIdx.x * 64;
    int b = m0 >> 13;
    size_t col0_4 = (size_t)(m0 & (M_ - 1)) >> 2;
    const float4* src4 = (const float4*)tfeat + (size_t)b * C_ * (M_ / 4);
    float acc[4][8] = {};
    for (int k0 = 0; k0 < C_; k0 += 32) {
        stage_direct64(As4, src4, M_ / 4, k0, col0_4, t);
        stage_transposeB((float*)Bs4, w2, C_, k0, t);
        __syncthreads();
        gemm_step64(As4, Bs4, tm, tn, acc);
        __syncthreads();
    }
    int c0 = tn * 8;
    float gc[8], bc[8];
    load8(g + c0, gc); load8(bb + c0, bc);
    const float* fb = f_t + (size_t)b * N_ * C_;
#pragma unroll
    for (int mm = 0; mm < 4; ++mm) {
        int m = m0 + tm * 4 + mm;
        int   i0 = idx3[m*3+0], i1 = idx3[m*3+1], i2 = idx3[m*3+2];
        float u0 = w3[m*3+0],  u1 = w3[m*3+1],  u2 = w3[m*3+2];
        float r0[8], r1[8], r2[8];
        load8(fb + (size_t)i0 * C_ + c0, r0);
        load8(fb + (size_t)i1 * C_ + c0, r1);
        load8(fb + (size_t)i2 * C_ + c0, r2);
        float o[8];
#pragma unroll
        for (int j = 0; j < 8; ++j) {
            float y = fmaxf(fmaf(acc[mm][j], gc[j] * BNINV, bc[j]), 0.f);
            o[j] = y + u0 * r0[j] + u1 * r1[j] + u2 * r2[j];
        }
        store8(x + (size_t)m * C_ + c0, o);
    }
}

// ---------------------------------------------------------------------------
// kNN (wave/query, lane-min merge + bitonic seed); qbase splits the grid
// across two dispatches for profile visibility (perf-neutral).
extern "C" __global__ __launch_bounds__(256) void k_knn(
    const float* __restrict__ cx, const float* __restrict__ cy,
    const float* __restrict__ cz, int* __restrict__ out_knn, int qbase)
{
    int q    = qbase + blockIdx.x * 4 + (threadIdx.x >> 6);
    int lane = threadIdx.x & 63;
    int b    = q >> 13;
    const float4* bx4 = (const float4*)(cx + (size_t)b * M_);
    const float4* by4 = (const float4*)(cy + (size_t)b * M_);
    const float4* bz4 = (const float4*)(cz + (size_t)b * M_);
    float qx = cx[q], qy = cy[q], qz = cz[q];

    unsigned long long list = ~0ULL;
    unsigned long long tau  = ~0ULL;
    float taud = 3e38f;

#define DIST(px,py,pz) ({ \
    float dx = (px)-qx, dy = (py)-qy, dz = (pz)-qz; \
    __fadd_rn(__fadd_rn(__fmul_rn(dx,dx), __fmul_rn(dy,dy)), __fmul_rn(dz,dz)); })

#define MIN4 (min(min(k0,k1),min(k2,k3)))

#define MERGELOOP { \
    unsigned long long mask = __ballot(mk < tau); \
    while (mask) { \
        int srcl = (int)__ffsll((long long)mask) - 1; \
        unsigned long long kk = __shfl(mk, srcl, 64); \
        unsigned long long below = __ballot(list < kk) & 0xFFFFull; \
        int pos = __popcll(below); \
        unsigned long long sh = __shfl_up(list, 1, 64); \
        if (lane == pos)                  list = kk; \
        else if (lane > pos && lane < K_) list = sh; \
        tau = __shfl(list, K_ - 1, 64); \
        if (lane == srcl) { \
            if      (k0 == mk) k0 = ~0ULL; \
            else if (k1 == mk) k1 = ~0ULL; \
            else if (k2 == mk) k2 = ~0ULL; \
            else               k3 = ~0ULL; \
            mk = MIN4; \
        } \
        mask = __ballot(mk < tau); \
    } \
    taud = __uint_as_float((unsigned)(tau >> 32)); }

    {   // iter 0: bitonic warm-up on the 64 k0-candidates, merge k1..k3
        float4 px = bx4[lane], py = by4[lane], pz = bz4[lane];
        float d0 = DIST(px.x,py.x,pz.x);
        float d1 = DIST(px.y,py.y,pz.y);
        float d2 = DIST(px.z,py.z,pz.z);
        float d3 = DIST(px.w,py.w,pz.w);
        unsigned long long j0 = (unsigned)(lane*4);
        unsigned long long k0 = ((unsigned long long)__float_as_uint(d0) << 32) | (j0+0);
        unsigned long long k1 = ((unsigned long long)__float_as_uint(d1) << 32) | (j0+1);
        unsigned long long k2 = ((unsigned long long)__float_as_uint(d2) << 32) | (j0+2);
        unsigned long long k3 = ((unsigned long long)__float_as_uint(d3) << 32) | (j0+3);
        unsigned long long key = k0;
#pragma unroll
        for (int k = 2; k <= 64; k <<= 1) {
#pragma unroll
            for (int j = k >> 1; j > 0; j >>= 1) {
                unsigned long long o = __shfl_xor(key, j, 64);
                bool up  = ((lane & k) == 0);
                bool low = ((lane & j) == 0);
                bool keepmin = (low == up);
                unsigned long long mn = (o < key) ? o : key;
                unsigned long long mx = (o < key) ? key : o;
                key = keepmin ? mn : mx;
            }
        }
        if (lane < K_) list = key;
        tau  = __shfl(list, K_ - 1, 64);
        taud = __uint_as_float((unsigned)(tau >> 32));
        k0 = ~0ULL;
        unsigned long long mk = MIN4;
        MERGELOOP
    }

    for (int i = 1; i < M_/256; ++i) {
        float4 px = bx4[i*64 + lane];
        float4 py = by4[i*64 + lane];
        float4 pz = bz4[i*64 + lane];
        float d0 = DIST(px.x,py.x,pz.x);
        float d1 = DIST(px.y,py.y,pz.y);
        float d2 = DIST(px.z,py.z,pz.z);
        float d3 = DIST(px.w,py.w,pz.w);
        bool any = (d0 <= taud) | (d1 <= taud) | (d2 <= taud) | (d3 <= taud);
        if (__ballot(any)) {
            unsigned long long j0 = (unsigned)(i*256 + lane*4);
            unsigned long long k0 = ((unsigned long long)__float_as_uint(d0) << 32) | (j0+0);
            unsigned long long k1 = ((unsigned long long)__float_as_uint(d1) << 32) | (j0+1);
            unsigned long long k2 = ((unsigned long long)__float_as_uint(d2) << 32) | (j0+2);
            unsigned long long k3 = ((unsigned long long)__float_as_uint(d3) << 32) | (j0+3);
            unsigned long long mk = MIN4;
            MERGELOOP
        }
    }
#undef MERGELOOP
#undef MIN4
#undef DIST
    if (lane < K_)
        out_knn[(size_t)q*K_ + lane] = (int)(unsigned)list;
}

// ---------------------------------------------------------------------------
// Fused x1 = relu(bn(x@W1.T)) kept in LDS (transposed), then q/k/v GEMMs.
extern "C" __global__ __launch_bounds__(256) void k_lqkv(
    const float* __restrict__ xin,
    const float* __restrict__ w1, const float* __restrict__ g1, const float* __restrict__ b1,
    const float* __restrict__ wq, const float* __restrict__ bq,
    const float* __restrict__ wk, const float* __restrict__ bk,
    const float* __restrict__ wv, const float* __restrict__ bv,
    float* __restrict__ q, float* __restrict__ k, float* __restrict__ v)
{
    __shared__ float  Asf[128 * 68];
    __shared__ float4 Bs4[32 * LDSB];
    int t = threadIdx.x, tm = t >> 4, tn = t & 15;
    int m0 = blockIdx.x * 64;
    int c0 = tn * 8;

    for (int k0 = 0; k0 < C_; k0 += 32)
        stage_transposeA(Asf + k0 * 68, xin, m0, C_, k0, t);

    float acc[4][8] = {};
    for (int k0 = 0; k0 < C_; k0 += 32) {
        stage_transposeB((float*)Bs4, w1, C_, k0, t);
        __syncthreads();
        gemm_step64((const float4*)Asf + k0 * 17, Bs4, tm, tn, acc);
        __syncthreads();
    }
    {
        float gc[8], bc[8];
        load8(g1 + c0, gc); load8(b1 + c0, bc);
#pragma unroll
        for (int mm = 0; mm < 4; ++mm) {
            int ml = tm * 4 + mm;
#pragma unroll
            for (int j = 0; j < 8; ++j)
                Asf[(c0 + j) * 68 + ml] = fmaxf(fmaf(acc[mm][j], gc[j] * BNINV, bc[j]), 0.f);
        }
    }
    __syncthreads();

#pragma unroll 1
    for (int which = 0; which < 3; ++which) {
        const float* W  = (which == 0) ? wq : (which == 1) ? wk : wv;
        const float* bi = (which == 0) ? bq : (which == 1) ? bk : bv;
        float*       out= (which == 0) ? q  : (which == 1) ? k  : v;
        float acc2[4][8] = {};
        for (int k0 = 0; k0 < C_; k0 += 32) {
            stage_transposeB((float*)Bs4, W, C_, k0, t);
            __syncthreads();
            gemm_step64((const float4*)Asf + k0 * 17, Bs4, tm, tn, acc2);
            __syncthreads();
        }
        float bc[8];
        load8(bi + c0, bc);
#pragma unroll
        for (int mm = 0; mm < 4; ++mm) {
            int m = m0 + tm * 4 + mm;
            float o[8];
#pragma unroll
            for (int j = 0; j < 8; ++j) o[j] = acc2[mm][j] + bc[j];
            store8(out + (size_t)m * C_ + c0, o);
        }
    }
}

// ---------------------------------------------------------------------------
// Attention core: batched gathers, pr MLP + w MLP + softmax + agg + bn2.
extern "C" __global__ __launch_bounds__(128) void k_attn2(
    const float* __restrict__ q, const float* __restrict__ kf, const float* __restrict__ vf,
    const int* __restrict__ knn, const float* __restrict__ txyz,
    const float* __restrict__ p1w, const float* __restrict__ p1b,
    const float* __restrict__ pbg, const float* __restrict__ pbb,
    const float* __restrict__ p2w, const float* __restrict__ p2b,
    const float* __restrict__ wb1g, const float* __restrict__ wb1b,
    const float* __restrict__ wl1, const float* __restrict__ wl1b,
    const float* __restrict__ wb2g, const float* __restrict__ wb2b,
    const float* __restrict__ wl2, const float* __restrict__ wl2b,
    const float* __restrict__ bn2g, const float* __restrict__ bn2b,
    float* __restrict__ x2out)
{
    __shared__ int   nbs[K_];
    __shared__ float scrd[K_][3];
    __shared__ float tshs[K_ * C_];
    __shared__ float svs [K_ * C_];
    __shared__ float wl1s[CS_ * 132];
    __shared__ float wl2s[CS_ * 17];
    __shared__ float ashs[K_ * 17];
    __shared__ float wshs[K_ * 17];

    int bm = blockIdx.x;
    int b  = bm >> 13;
    int c  = threadIdx.x;

#pragma unroll
    for (int i = 0; i < 16; ++i) {
        int idx = c + i * 128;
        wl1s[(idx >> 7) * 132 + (idx & 127)] = wl1[idx];
    }
    {
        int i1 = c, i2 = c + 128;
        if (i1 < 256) wl2s[(i1 >> 4) * 17 + (i1 & 15)] = wl2[i1];
        if (i2 < 256) wl2s[(i2 >> 4) * 17 + (i2 & 15)] = wl2[i2];
    }
    if (c < K_) nbs[c] = knn[(size_t)bm * K_ + c];
    __syncthreads();

    float kfv[K_], vfv[K_];
    const float* txb = txyz + (size_t)b * M_ * 3;
#pragma unroll
    for (int t = 0; t < K_; ++t) {
        size_t nrow = ((size_t)b * M_ + nbs[t]) * C_ + c;
        kfv[t] = kf[nrow];
        vfv[t] = vf[nrow];
    }
    if (c < 48) {
        int t = c / 3, comp = c - t * 3;
        scrd[t][comp] = txb[nbs[t] * 3 + comp];
    }

    float qc = q[(size_t)bm * C_ + c];
    float qx = txyz[(size_t)bm*3+0], qy = txyz[(size_t)bm*3+1], qz = txyz[(size_t)bm*3+2];
    float p2w0 = p2w[c*3+0], p2w1 = p2w[c*3+1], p2w2 = p2w[c*3+2], p2bc = p2b[c];
    float b1s = wb1g[c]*BNINV, b1b = wb1b[c];
    float a00=p1w[0],a01=p1w[1],a02=p1w[2],a10=p1w[3],a11=p1w[4],a12=p1w[5],a20=p1w[6],a21=p1w[7],a22=p1w[8];
    float pb0=p1b[0], pb1=p1b[1], pb2=p1b[2];
    float g0=pbg[0]*BNINV, g1=pbg[1]*BNINV, g2=pbg[2]*BNINV;
    float hb0=pbb[0], hb1=pbb[1], hb2=pbb[2];
    __syncthreads();

#pragma unroll
    for (int t = 0; t < K_; ++t) {
        float dx = scrd[t][0]-qx, dy = scrd[t][1]-qy, dz = scrd[t][2]-qz;
        float h0 = fmaxf(fmaf(fmaf(a02,dz, fmaf(a01,dy, fmaf(a00,dx, pb0))), g0, hb0), 0.f);
        float h1 = fmaxf(fmaf(fmaf(a12,dz, fmaf(a11,dy, fmaf(a10,dx, pb1))), g1, hb1), 0.f);
        float h2 = fmaxf(fmaf(fmaf(a22,dz, fmaf(a21,dy, fmaf(a20,dx, pb2))), g2, hb2), 0.f);
        float pr = fmaf(p2w2,h2, fmaf(p2w1,h1, fmaf(p2w0,h0, p2bc)));
        float r = kfv[t] - qc + pr;
        tshs[t*C_ + c] = fmaxf(fmaf(r, b1s, b1b), 0.f);
        svs [t*C_ + c] = vfv[t] + pr;
    }
    __syncthreads();

    {
        int s = c >> 3, u = c & 7;
        float w1b = wl1b[s], gg = wb2g[s]*BNINV, gb = wb2b[s];
        for (int nb = 0; nb < K_; ++nb) {
            float a = 0.f;
#pragma unroll
            for (int i = 0; i < 16; ++i)
                a = fmaf(wl1s[s*132 + u + 8*i], tshs[nb*C_ + u + 8*i], a);
            a += __shfl_down(a, 4, 8);
            a += __shfl_down(a, 2, 8);
            a += __shfl_down(a, 1, 8);
            if (u == 0)
                ashs[nb*17 + s] = fmaxf(fmaf(a + w1b, gg, gb), 0.f);
        }
    }
    __syncthreads();

    {
        int nb = c >> 3;
        int cs1 = c & 7, cs2 = (c & 7) + 8;
        float a1 = wl2b[cs1], a2 = wl2b[cs2];
#pragma unroll
        for (int j = 0; j < CS_; ++j) {
            float av = ashs[nb*17 + j];
            a1 = fmaf(wl2s[cs1*17 + j], av, a1);
            a2 = fmaf(wl2s[cs2*17 + j], av, a2);
        }
        wshs[nb*17 + cs1] = a1;
        wshs[nb*17 + cs2] = a2;
    }
    __syncthreads();

    if (c < CS_) {
        float mx = -3e38f;
#pragma unroll
        for (int nb = 0; nb < K_; ++nb) mx = fmaxf(mx, wshs[nb*17 + c]);
        float ssum = 0.f;
#pragma unroll
        for (int nb = 0; nb < K_; ++nb) {
            float e = __expf(wshs[nb*17 + c] - mx);
            wshs[nb*17 + c] = e; ssum += e;
        }
        float inv = 1.f / ssum;
#pragma unroll
        for (int nb = 0; nb < K_; ++nb) wshs[nb*17 + c] *= inv;
    }
    __syncthreads();

    float agg = 0.f;
    int cs = c & (CS_ - 1);
#pragma unroll
    for (int nb = 0; nb < K_; ++nb)
        agg = fmaf(svs[nb*C_ + c], wshs[nb*17 + cs], agg);
    float x2 = fmaxf(fmaf(agg, bn2g[c]*BNINV, bn2b[c]), 0.f);
    x2out[(size_t)bm * C_ + c] = x2;
}

// ---------------------------------------------------------------------------
// out[b][c][m] = relu(bn3(x2 @ l3w.T) + identity)   (transposed store)
extern "C" __global__ __launch_bounds__(256) void k_lin3(
    const float* __restrict__ x2, const float* __restrict__ w,
    const float* __restrict__ g, const float* __restrict__ bb,
    const float* __restrict__ xid, float* __restrict__ out)
{
    __shared__ float4 As4[32 * LDSA], Bs4[32 * LDSB];
    int t = threadIdx.x, tm = t >> 4, tn = t & 15;
    int m0 = blockIdx.x * 64;
    int b  = m0 >> 13;
    float acc[4][8] = {};
    for (int k0 = 0; k0 < C_; k0 += 32) {
        stage_transposeA((float*)As4, x2, m0, C_, k0, t);
        stage_transposeB((float*)Bs4, w, C_, k0, t);
        __syncthreads();
        gemm_step64(As4, Bs4, tm, tn, acc);
        __syncthreads();
    }
    int c0 = tn * 8;
    float gc[8], bc[8];
    load8(g + c0, gc); load8(bb + c0, bc);
#pragma unroll
    for (int mm = 0; mm < 4; ++mm) {
        int m = m0 + tm * 4 + mm;
        float idv[8];
        load8(xid + (size_t)m * C_ + c0, idv);
#pragma unroll
        for (int j = 0; j < 8; ++j) {
            float x3 = fmaf(acc[mm][j], gc[j] * BNINV, bc[j]);
            acc[mm][j] = fmaxf(x3 + idv[j], 0.f);
        }
    }
    int mloc = (m0 & (M_ - 1)) + tm * 4;
    float* ob = out + (size_t)b * C_ * M_;
#pragma unroll
    for (int j = 0; j < 8; ++j) {
        float* p = ob + (size_t)(c0 + j) * M_ + mloc;
        *(float4*)p = make_float4(acc[0][j], acc[1][j], acc[2][j], acc[3][j]);
    }
}

// ---------------------------------------------------------------------------
extern "C" void kernel_launch(void* const* d_in, const int* in_sizes, int n_in,
                              void* d_out, int out_size, void* d_ws, size_t ws_size,
                              hipStream_t stream)
{
    const float* xyz   = (const float*)d_in[0];
    const float* feat  = (const float*)d_in[1];
    const float* txyz  = (const float*)d_in[2];
    const float* tfeat = (const float*)d_in[3];
    const float* tu1w  = (const float*)d_in[4];
    const float* tu1g  = (const float*)d_in[5];
    const float* tu1b  = (const float*)d_in[6];
    const float* tu2w  = (const float*)d_in[7];
    const float* tu2g  = (const float*)d_in[8];
    const float* tu2b  = (const float*)d_in[9];
    const float* bl1w  = (const float*)d_in[10];
    const float* bl1g  = (const float*)d_in[11];
    const float* bl1b  = (const float*)d_in[12];
    const float* wq    = (const float*)d_in[13];
    const float* bq    = (const float*)d_in[14];
    const float* wk    = (const float*)d_in[15];
    const float* bk    = (const float*)d_in[16];
    const float* wv    = (const float*)d_in[17];
    const float* bv    = (const float*)d_in[18];
    const float* p1w   = (const float*)d_in[19];
    const float* p1b   = (const float*)d_in[20];
    const float* pbg   = (const float*)d_in[21];
    const float* pbb   = (const float*)d_in[22];
    const float* p2w   = (const float*)d_in[23];
    const float* p2b   = (const float*)d_in[24];
    const float* wb1g  = (const float*)d_in[25];
    const float* wb1b  = (const float*)d_in[26];
    const float* wl1   = (const float*)d_in[27];
    const float* wl1b  = (const float*)d_in[28];
    const float* wb2g  = (const float*)d_in[29];
    const float* wb2b  = (const float*)d_in[30];
    const float* wl2   = (const float*)d_in[31];
    const float* wl2b  = (const float*)d_in[32];
    const float* bn2g  = (const float*)d_in[33];
    const float* bn2b  = (const float*)d_in[34];
    const float* l3w   = (const float*)d_in[35];
    const float* bn3g  = (const float*)d_in[36];
    const float* bn3b  = (const float*)d_in[37];

    char* ws = (char*)d_ws;
    size_t off = 0;
    auto alloc = [&](size_t bytes) { void* p = ws + off; off += (bytes + 255) & ~(size_t)255; return p; };
    float* f_t  = (float*)alloc(sizeof(float) * B_ * N_ * C_);
    int*   idx3 = (int*)  alloc(sizeof(int)   * B_ * M_ * 3);
    float* w3   = (float*)alloc(sizeof(float) * B_ * M_ * 3);
    float* x    = (float*)alloc(sizeof(float) * B_ * M_ * C_);
    float* x2   = (float*)alloc(sizeof(float) * B_ * M_ * C_);
    float* qb   = (float*)alloc(sizeof(float) * B_ * M_ * C_);
    float* kb   = (float*)alloc(sizeof(float) * B_ * M_ * C_);
    float* vb   = (float*)alloc(sizeof(float) * B_ * M_ * C_);
    int*   knn  = (int*)  alloc(sizeof(int)   * B_ * M_ * K_);
    float* cx   = (float*)alloc(sizeof(float) * B_ * M_);
    float* cy   = (float*)alloc(sizeof(float) * B_ * M_);
    float* cz   = (float*)alloc(sizeof(float) * B_ * M_);

    k_soa     <<<(B_*M_+255)/256, 256, 0, stream>>>(txyz, cx, cy, cz);
    k_f       <<<B_*N_/64,        256, 0, stream>>>(feat, tu1w, tu1g, tu1b, f_t);
    k_three_nn<<<B_*M_/4,         256, 0, stream>>>(xyz, txyz, idx3, w3);
    k_feat    <<<B_*M_/64,        256, 0, stream>>>(tfeat, tu2w, tu2g, tu2b, f_t, idx3, w3, x);
    k_knn     <<<B_*M_/8,         256, 0, stream>>>(cx, cy, cz, knn, 0);
    k_knn     <<<B_*M_/8,         256, 0, stream>>>(cx, cy, cz, knn, B_*M_/2);
    k_lqkv    <<<B_*M_/64,        256, 0, stream>>>(x, bl1w, bl1g, bl1b,
                                                    wq, bq, wk, bk, wv, bv, qb, kb, vb);
    k_attn2   <<<B_*M_,           128, 0, stream>>>(qb, kb, vb, knn, txyz,
                                                    p1w, p1b, pbg, pbb, p2w, p2b,
                                                    wb1g, wb1b, wl1, wl1b, wb2g, wb2b, wl2, wl2b,
                                                    bn2g, bn2b, x2);
    k_lin3    <<<B_*M_/64,        256, 0, stream>>>(x2, l3w, bn3g, bn3b, x, (float*)d_out);
}

// Round 21
// 339.569 us; speedup vs baseline: 1.2595x; 1.1646x over previous
//
#include <hip/hip_runtime.h>
#include <cstddef>
#include <cstdint>

#define B_  2
#define N_  2048
#define M_  8192
#define C1_ 256
#define C_  128
#define K_  16
#define CS_ 16

// 1/sqrt(1+1e-5)
#define BNINV 0.9999950000374997f

// ======================= tiled fp32 GEMM machinery =========================
// BM=64, BN=128, BK=32, 256 threads, 4x8 micro-tile per thread.
#define LDSA 17   // float4 stride of A k-row (64 f + 4 pad)
#define LDSB 33   // float4 stride of B k-row (128 f + 4 pad)

__device__ __forceinline__ void stage_direct64(float4* Ls4, const float4* src4,
                                               size_t row_stride4, int k0,
                                               size_t col0_4, int t)
{
#pragma unroll
    for (int i = 0; i < 2; ++i) {
        int idx = t + i * 256;
        int kk = idx >> 4, f4 = idx & 15;
        Ls4[kk * LDSA + f4] = src4[(size_t)(k0 + kk) * row_stride4 + col0_4 + f4];
    }
}

__device__ __forceinline__ void stage_transposeA(float* Lsf, const float* src,
                                                 int row0, int ldk, int k0, int t)
{
    int u = t & 7, r = t >> 3;
#pragma unroll
    for (int i = 0; i < 2; ++i) {
        int row = r + i * 32;
        float4 v = *(const float4*)(src + (size_t)(row0 + row) * ldk + k0 + u * 4);
        Lsf[(u * 4 + 0) * 68 + row] = v.x;
        Lsf[(u * 4 + 1) * 68 + row] = v.y;
        Lsf[(u * 4 + 2) * 68 + row] = v.z;
        Lsf[(u * 4 + 3) * 68 + row] = v.w;
    }
}

__device__ __forceinline__ void stage_transposeB(float* Lsf, const float* src,
                                                 int ldk, int k0, int t)
{
    int u = t & 7, r = t >> 3;
#pragma unroll
    for (int i = 0; i < 4; ++i) {
        int row = r + i * 32;
        float4 v = *(const float4*)(src + (size_t)row * ldk + k0 + u * 4);
        Lsf[(u * 4 + 0) * 132 + row] = v.x;
        Lsf[(u * 4 + 1) * 132 + row] = v.y;
        Lsf[(u * 4 + 2) * 132 + row] = v.z;
        Lsf[(u * 4 + 3) * 132 + row] = v.w;
    }
}

__device__ __forceinline__ void gemm_step64(const float4* As4, const float4* Bs4,
                                            int tm, int tn, float acc[4][8])
{
#pragma unroll 4
    for (int kk = 0; kk < 32; ++kk) {
        float4 a0 = As4[kk * LDSA + tm];
        float4 b0 = Bs4[kk * LDSB + tn * 2];
        float4 b1 = Bs4[kk * LDSB + tn * 2 + 1];
        float av[4] = {a0.x,a0.y,a0.z,a0.w};
        float bv[8] = {b0.x,b0.y,b0.z,b0.w,b1.x,b1.y,b1.z,b1.w};
#pragma unroll
        for (int i = 0; i < 4; ++i)
#pragma unroll
            for (int j = 0; j < 8; ++j)
                acc[i][j] = fmaf(av[i], bv[j], acc[i][j]);
    }
}

__device__ __forceinline__ void load8(const float* p, float* v)
{
    float4 a = *(const float4*)p, b = *(const float4*)(p + 4);
    v[0]=a.x; v[1]=a.y; v[2]=a.z; v[3]=a.w; v[4]=b.x; v[5]=b.y; v[6]=b.z; v[7]=b.w;
}
__device__ __forceinline__ void store8(float* p, const float* v)
{
    *(float4*)p       = make_float4(v[0],v[1],v[2],v[3]);
    *(float4*)(p + 4) = make_float4(v[4],v[5],v[6],v[7]);
}

// ---------------------------------------------------------------------------
// f_t[bn][c] = relu(bn1(sum_j W1[c][j] * F[b][j][n]))   (A direct, K=256)
extern "C" __global__ __launch_bounds__(256) void k_f(
    const float* __restrict__ feature, const float* __restrict__ w,
    const float* __restrict__ g, const float* __restrict__ bb,
    float* __restrict__ f_t)
{
    __shared__ float4 As4[32 * LDSA], Bs4[32 * LDSB];
    int t = threadIdx.x, tm = t >> 4, tn = t & 15;
    int m0 = blockIdx.x * 64;
    int b = m0 >> 11;
    size_t col0_4 = (size_t)(m0 & (N_ - 1)) >> 2;
    const float4* src4 = (const float4*)feature + (size_t)b * C1_ * (N_ / 4);
    float acc[4][8] = {};
    for (int k0 = 0; k0 < C1_; k0 += 32) {
        stage_direct64(As4, src4, N_ / 4, k0, col0_4, t);
        stage_transposeB((float*)Bs4, w, C1_, k0, t);
        __syncthreads();
        gemm_step64(As4, Bs4, tm, tn, acc);
        __syncthreads();
    }
    int c0 = tn * 8;
    float gc[8], bc[8];
    load8(g + c0, gc); load8(bb + c0, bc);
#pragma unroll
    for (int mm = 0; mm < 4; ++mm) {
        int m = m0 + tm * 4 + mm;
        float o[8];
#pragma unroll
        for (int j = 0; j < 8; ++j)
            o[j] = fmaxf(fmaf(acc[mm][j], gc[j] * BNINV, bc[j]), 0.f);
        store8(f_t + (size_t)m * C_ + c0, o);
    }
}

// ---------------------------------------------------------------------------
// SoA transpose of target_xyz
extern "C" __global__ __launch_bounds__(256) void k_soa(
    const float* __restrict__ txyz,
    float* __restrict__ cx, float* __restrict__ cy, float* __restrict__ cz)
{
    int t = blockIdx.x * 256 + threadIdx.x;
    if (t < B_ * M_) {
        cx[t] = txyz[t*3+0];
        cy[t] = txyz[t*3+1];
        cz[t] = txyz[t*3+2];
    }
}

// ---------------------------------------------------------------------------
// three_nn (wave/query, packed u64 keys)
extern "C" __global__ __launch_bounds__(256) void k_three_nn(
    const float* __restrict__ xyz, const float* __restrict__ txyz,
    int* __restrict__ idx3, float* __restrict__ w3)
{
    int q    = blockIdx.x * 4 + (threadIdx.x >> 6);
    int lane = threadIdx.x & 63;
    int b    = q / M_;
    const float* src = xyz + (size_t)b * N_ * 3;
    float qx = txyz[(size_t)q*3+0], qy = txyz[(size_t)q*3+1], qz = txyz[(size_t)q*3+2];

    unsigned long long p0 = ~0ULL, p1 = ~0ULL, p2 = ~0ULL;
    for (int i = 0; i < N_/64; ++i) {
        int j = lane + (i << 6);
        float dx = src[j*3+0]-qx, dy = src[j*3+1]-qy, dz = src[j*3+2]-qz;
        float d = __fadd_rn(__fadd_rn(__fmul_rn(dx,dx), __fmul_rn(dy,dy)), __fmul_rn(dz,dz));
        unsigned long long key = ((unsigned long long)__float_as_uint(d) << 32) | (unsigned)j;
        if (key < p2) {
            p2 = key;
            if (p2 < p1) { unsigned long long t = p1; p1 = p2; p2 = t; }
            if (p1 < p0) { unsigned long long t = p0; p0 = p1; p1 = t; }
        }
    }
    unsigned long long wmin[3];
    unsigned long long h = p0;
#pragma unroll
    for (int r = 0; r < 3; ++r) {
        unsigned long long w = h;
#pragma unroll
        for (int s = 1; s < 64; s <<= 1) {
            unsigned long long o = __shfl_xor(w, s, 64);
            w = (o < w) ? o : w;
        }
        wmin[r] = w;
        if (h == w) { p0 = p1; p1 = p2; p2 = ~0ULL; h = p0; }
    }
    if (lane == 0) {
        float d0 = __uint_as_float((unsigned)(wmin[0] >> 32));
        float d1 = __uint_as_float((unsigned)(wmin[1] >> 32));
        float d2 = __uint_as_float((unsigned)(wmin[2] >> 32));
        float s0 = sqrtf(fmaxf(d0, 0.f)), s1 = sqrtf(fmaxf(d1, 0.f)), s2 = sqrtf(fmaxf(d2, 0.f));
        float r0 = 1.f/(s0+1e-8f), r1 = 1.f/(s1+1e-8f), r2 = 1.f/(s2+1e-8f);
        float inv = 1.f/(r0+r1+r2);
        idx3[(size_t)q*3+0] = (int)(unsigned)wmin[0];
        idx3[(size_t)q*3+1] = (int)(unsigned)wmin[1];
        idx3[(size_t)q*3+2] = (int)(unsigned)wmin[2];
        w3[(size_t)q*3+0] = r0*inv; w3[(size_t)q*3+1] = r1*inv; w3[(size_t)q*3+2] = r2*inv;
    }
}

// ---------------------------------------------------------------------------
// x[m][c] = relu(bn2(tu_lin2_w @ target_feature)) + three_interpolate(f_t)
extern "C" __global__ __launch_bounds__(256) void k_feat(
    const float* __restrict__ tfeat, const float* __restrict__ w2,
    const float* __restrict__ g, const float* __restrict__ bb,
    const float* __restrict__ f_t, const int* __restrict__ idx3,
    const float* __restrict__ w3, float* __restrict__ x)
{
    __shared__ float4 As4[32 * LDSA], Bs4[32 * LDSB];
    int t = threadIdx.x, tm = t >> 4, tn = t & 15;
    int m0 = blockIdx.x * 64;
    int b = m0 >> 13;
    size_t col0_4 = (size_t)(m0 & (M_ - 1)) >> 2;
    const float4* src4 = (const float4*)tfeat + (size_t)b * C_ * (M_ / 4);
    float acc[4][8] = {};
    for (int k0 = 0; k0 < C_; k0 += 32) {
        stage_direct64(As4, src4, M_ / 4, k0, col0_4, t);
        stage_transposeB((float*)Bs4, w2, C_, k0, t);
        __syncthreads();
        gemm_step64(As4, Bs4, tm, tn, acc);
        __syncthreads();
    }
    int c0 = tn * 8;
    float gc[8], bc[8];
    load8(g + c0, gc); load8(bb + c0, bc);
    const float* fb = f_t + (size_t)b * N_ * C_;
#pragma unroll
    for (int mm = 0; mm < 4; ++mm) {
        int m = m0 + tm * 4 + mm;
        int   i0 = idx3[m*3+0], i1 = idx3[m*3+1], i2 = idx3[m*3+2];
        float u0 = w3[m*3+0],  u1 = w3[m*3+1],  u2 = w3[m*3+2];
        float r0[8], r1[8], r2[8];
        load8(fb + (size_t)i0 * C_ + c0, r0);
        load8(fb + (size_t)i1 * C_ + c0, r1);
        load8(fb + (size_t)i2 * C_ + c0, r2);
        float o[8];
#pragma unroll
        for (int j = 0; j < 8; ++j) {
            float y = fmaxf(fmaf(acc[mm][j], gc[j] * BNINV, bc[j]), 0.f);
            o[j] = y + u0 * r0[j] + u1 * r1[j] + u2 * r2[j];
        }
        store8(x + (size_t)m * C_ + c0, o);
    }
}

// ---------------------------------------------------------------------------
// kNN (wave/query, lane-min merge + bitonic seed) — single dispatch
extern "C" __global__ __launch_bounds__(256) void k_knn(
    const float* __restrict__ cx, const float* __restrict__ cy,
    const float* __restrict__ cz, int* __restrict__ out_knn)
{
    int q    = blockIdx.x * 4 + (threadIdx.x >> 6);
    int lane = threadIdx.x & 63;
    int b    = q >> 13;
    const float4* bx4 = (const float4*)(cx + (size_t)b * M_);
    const float4* by4 = (const float4*)(cy + (size_t)b * M_);
    const float4* bz4 = (const float4*)(cz + (size_t)b * M_);
    float qx = cx[q], qy = cy[q], qz = cz[q];

    unsigned long long list = ~0ULL;
    unsigned long long tau  = ~0ULL;
    float taud = 3e38f;

#define DIST(px,py,pz) ({ \
    float dx = (px)-qx, dy = (py)-qy, dz = (pz)-qz; \
    __fadd_rn(__fadd_rn(__fmul_rn(dx,dx), __fmul_rn(dy,dy)), __fmul_rn(dz,dz)); })

#define MIN4 (min(min(k0,k1),min(k2,k3)))

#define MERGELOOP { \
    unsigned long long mask = __ballot(mk < tau); \
    while (mask) { \
        int srcl = (int)__ffsll((long long)mask) - 1; \
        unsigned long long kk = __shfl(mk, srcl, 64); \
        unsigned long long below = __ballot(list < kk) & 0xFFFFull; \
        int pos = __popcll(below); \
        unsigned long long sh = __shfl_up(list, 1, 64); \
        if (lane == pos)                  list = kk; \
        else if (lane > pos && lane < K_) list = sh; \
        tau = __shfl(list, K_ - 1, 64); \
        if (lane == srcl) { \
            if      (k0 == mk) k0 = ~0ULL; \
            else if (k1 == mk) k1 = ~0ULL; \
            else if (k2 == mk) k2 = ~0ULL; \
            else               k3 = ~0ULL; \
            mk = MIN4; \
        } \
        mask = __ballot(mk < tau); \
    } \
    taud = __uint_as_float((unsigned)(tau >> 32)); }

    {   // iter 0: bitonic warm-up on the 64 k0-candidates, merge k1..k3
        float4 px = bx4[lane], py = by4[lane], pz = bz4[lane];
        float d0 = DIST(px.x,py.x,pz.x);
        float d1 = DIST(px.y,py.y,pz.y);
        float d2 = DIST(px.z,py.z,pz.z);
        float d3 = DIST(px.w,py.w,pz.w);
        unsigned long long j0 = (unsigned)(lane*4);
        unsigned long long k0 = ((unsigned long long)__float_as_uint(d0) << 32) | (j0+0);
        unsigned long long k1 = ((unsigned long long)__float_as_uint(d1) << 32) | (j0+1);
        unsigned long long k2 = ((unsigned long long)__float_as_uint(d2) << 32) | (j0+2);
        unsigned long long k3 = ((unsigned long long)__float_as_uint(d3) << 32) | (j0+3);
        unsigned long long key = k0;
#pragma unroll
        for (int k = 2; k <= 64; k <<= 1) {
#pragma unroll
            for (int j = k >> 1; j > 0; j >>= 1) {
                unsigned long long o = __shfl_xor(key, j, 64);
                bool up  = ((lane & k) == 0);
                bool low = ((lane & j) == 0);
                bool keepmin = (low == up);
                unsigned long long mn = (o < key) ? o : key;
                unsigned long long mx = (o < key) ? key : o;
                key = keepmin ? mn : mx;
            }
        }
        if (lane < K_) list = key;
        tau  = __shfl(list, K_ - 1, 64);
        taud = __uint_as_float((unsigned)(tau >> 32));
        k0 = ~0ULL;
        unsigned long long mk = MIN4;
        MERGELOOP
    }

    for (int i = 1; i < M_/256; ++i) {
        float4 px = bx4[i*64 + lane];
        float4 py = by4[i*64 + lane];
        float4 pz = bz4[i*64 + lane];
        float d0 = DIST(px.x,py.x,pz.x);
        float d1 = DIST(px.y,py.y,pz.y);
        float d2 = DIST(px.z,py.z,pz.z);
        float d3 = DIST(px.w,py.w,pz.w);
        bool any = (d0 <= taud) | (d1 <= taud) | (d2 <= taud) | (d3 <= taud);
        if (__ballot(any)) {
            unsigned long long j0 = (unsigned)(i*256 + lane*4);
            unsigned long long k0 = ((unsigned long long)__float_as_uint(d0) << 32) | (j0+0);
            unsigned long long k1 = ((unsigned long long)__float_as_uint(d1) << 32) | (j0+1);
            unsigned long long k2 = ((unsigned long long)__float_as_uint(d2) << 32) | (j0+2);
            unsigned long long k3 = ((unsigned long long)__float_as_uint(d3) << 32) | (j0+3);
            unsigned long long mk = MIN4;
            MERGELOOP
        }
    }
#undef MERGELOOP
#undef MIN4
#undef DIST
    if (lane < K_)
        out_knn[(size_t)q*K_ + lane] = (int)(unsigned)list;
}

// ---------------------------------------------------------------------------
// Fused x1 = relu(bn(x@W1.T)) kept in LDS (transposed), then q/k/v GEMMs.
extern "C" __global__ __launch_bounds__(256) void k_lqkv(
    const float* __restrict__ xin,
    const float* __restrict__ w1, const float* __restrict__ g1, const float* __restrict__ b1,
    const float* __restrict__ wq, const float* __restrict__ bq,
    const float* __restrict__ wk, const float* __restrict__ bk,
    const float* __restrict__ wv, const float* __restrict__ bv,
    float* __restrict__ q, float* __restrict__ k, float* __restrict__ v)
{
    __shared__ float  Asf[128 * 68];
    __shared__ float4 Bs4[32 * LDSB];
    int t = threadIdx.x, tm = t >> 4, tn = t & 15;
    int m0 = blockIdx.x * 64;
    int c0 = tn * 8;

    for (int k0 = 0; k0 < C_; k0 += 32)
        stage_transposeA(Asf + k0 * 68, xin, m0, C_, k0, t);

    float acc[4][8] = {};
    for (int k0 = 0; k0 < C_; k0 += 32) {
        stage_transposeB((float*)Bs4, w1, C_, k0, t);
        __syncthreads();
        gemm_step64((const float4*)Asf + k0 * 17, Bs4, tm, tn, acc);
        __syncthreads();
    }
    {
        float gc[8], bc[8];
        load8(g1 + c0, gc); load8(b1 + c0, bc);
#pragma unroll
        for (int mm = 0; mm < 4; ++mm) {
            int ml = tm * 4 + mm;
#pragma unroll
            for (int j = 0; j < 8; ++j)
                Asf[(c0 + j) * 68 + ml] = fmaxf(fmaf(acc[mm][j], gc[j] * BNINV, bc[j]), 0.f);
        }
    }
    __syncthreads();

#pragma unroll 1
    for (int which = 0; which < 3; ++which) {
        const float* W  = (which == 0) ? wq : (which == 1) ? wk : wv;
        const float* bi = (which == 0) ? bq : (which == 1) ? bk : bv;
        float*       out= (which == 0) ? q  : (which == 1) ? k  : v;
        float acc2[4][8] = {};
        for (int k0 = 0; k0 < C_; k0 += 32) {
            stage_transposeB((float*)Bs4, W, C_, k0, t);
            __syncthreads();
            gemm_step64((const float4*)Asf + k0 * 17, Bs4, tm, tn, acc2);
            __syncthreads();
        }
        float bc[8];
        load8(bi + c0, bc);
#pragma unroll
        for (int mm = 0; mm < 4; ++mm) {
            int m = m0 + tm * 4 + mm;
            float o[8];
#pragma unroll
            for (int j = 0; j < 8; ++j) o[j] = acc2[mm][j] + bc[j];
            store8(out + (size_t)m * C_ + c0, o);
        }
    }
}

// ---------------------------------------------------------------------------
// Attention core v3: TWO points per 256-thread block (p = tid>>7, c = tid&127);
// sv kept in registers; weight staging amortized over 2 points.
extern "C" __global__ __launch_bounds__(256) void k_attn2(
    const float* __restrict__ q, const float* __restrict__ kf, const float* __restrict__ vf,
    const int* __restrict__ knn, const float* __restrict__ txyz,
    const float* __restrict__ p1w, const float* __restrict__ p1b,
    const float* __restrict__ pbg, const float* __restrict__ pbb,
    const float* __restrict__ p2w, const float* __restrict__ p2b,
    const float* __restrict__ wb1g, const float* __restrict__ wb1b,
    const float* __restrict__ wl1, const float* __restrict__ wl1b,
    const float* __restrict__ wb2g, const float* __restrict__ wb2b,
    const float* __restrict__ wl2, const float* __restrict__ wl2b,
    const float* __restrict__ bn2g, const float* __restrict__ bn2b,
    float* __restrict__ x2out)
{
    __shared__ int   nbs[2][K_];
    __shared__ float scrd[2][K_][3];
    __shared__ float tshs[2][K_ * C_];
    __shared__ float wl1s[CS_ * 132];
    __shared__ float wl2s[CS_ * 17];
    __shared__ float ashs[2][K_ * 17];
    __shared__ float wshs[2][K_ * 17];

    int tid = threadIdx.x;
    int p   = tid >> 7;             // 0 or 1
    int c   = tid & 127;
    int bm  = blockIdx.x * 2 + p;
    int b   = bm >> 13;

    // stage wl1 (16x128) and wl2 (16x16) with all 256 threads
#pragma unroll
    for (int i = 0; i < 8; ++i) {
        int idx = tid + i * 256;
        wl1s[(idx >> 7) * 132 + (idx & 127)] = wl1[idx];
    }
    wl2s[(tid >> 4) * 17 + (tid & 15)] = wl2[tid & 255];
    if (c < K_) nbs[p][c] = knn[(size_t)bm * K_ + c];
    __syncthreads();

    // issue ALL gathers for this point (32 loads in flight) + neighbor coords
    float kfv[K_], svr[K_];
    const float* txb = txyz + (size_t)b * M_ * 3;
#pragma unroll
    for (int t = 0; t < K_; ++t) {
        size_t nrow = ((size_t)b * M_ + nbs[p][t]) * C_ + c;
        kfv[t] = kf[nrow];
        svr[t] = vf[nrow];
    }
    if (c < 48) {
        int t = c / 3, comp = c - t * 3;
        scrd[p][t][comp] = txb[nbs[p][t] * 3 + comp];
    }

    float qc = q[(size_t)bm * C_ + c];
    float qx = txyz[(size_t)bm*3+0], qy = txyz[(size_t)bm*3+1], qz = txyz[(size_t)bm*3+2];
    float p2w0 = p2w[c*3+0], p2w1 = p2w[c*3+1], p2w2 = p2w[c*3+2], p2bc = p2b[c];
    float b1s = wb1g[c]*BNINV, b1b = wb1b[c];
    float a00=p1w[0],a01=p1w[1],a02=p1w[2],a10=p1w[3],a11=p1w[4],a12=p1w[5],a20=p1w[6],a21=p1w[7],a22=p1w[8];
    float pb0=p1b[0], pb1=p1b[1], pb2=p1b[2];
    float g0=pbg[0]*BNINV, g1=pbg[1]*BNINV, g2=pbg[2]*BNINV;
    float hb0=pbb[0], hb1=pbb[1], hb2=pbb[2];
    __syncthreads();

    // phase 1: per-neighbor pr, tsh (LDS), sv (register)
#pragma unroll
    for (int t = 0; t < K_; ++t) {
        float dx = scrd[p][t][0]-qx, dy = scrd[p][t][1]-qy, dz = scrd[p][t][2]-qz;
        float h0 = fmaxf(fmaf(fmaf(a02,dz, fmaf(a01,dy, fmaf(a00,dx, pb0))), g0, hb0), 0.f);
        float h1 = fmaxf(fmaf(fmaf(a12,dz, fmaf(a11,dy, fmaf(a10,dx, pb1))), g1, hb1), 0.f);
        float h2 = fmaxf(fmaf(fmaf(a22,dz, fmaf(a21,dy, fmaf(a20,dx, pb2))), g2, hb2), 0.f);
        float pr = fmaf(p2w2,h2, fmaf(p2w1,h1, fmaf(p2w0,h0, p2bc)));
        float r = kfv[t] - qc + pr;
        tshs[p][t*C_ + c] = fmaxf(fmaf(r, b1s, b1b), 0.f);
        svr[t] += pr;
    }
    __syncthreads();

    // phase 2: 16x128 matvec for all neighbors of this point
    {
        int s = c >> 3, u = c & 7;
        float w1b = wl1b[s], gg = wb2g[s]*BNINV, gb = wb2b[s];
        for (int nb = 0; nb < K_; ++nb) {
            float a = 0.f;
#pragma unroll
            for (int i = 0; i < 16; ++i)
                a = fmaf(wl1s[s*132 + u + 8*i], tshs[p][nb*C_ + u + 8*i], a);
            a += __shfl_down(a, 4, 8);
            a += __shfl_down(a, 2, 8);
            a += __shfl_down(a, 1, 8);
            if (u == 0)
                ashs[p][nb*17 + s] = fmaxf(fmaf(a + w1b, gg, gb), 0.f);
        }
    }
    __syncthreads();

    // phase 3: 16x16 matvec
    {
        int nb = c >> 3;
        int cs1 = c & 7, cs2 = (c & 7) + 8;
        float a1 = wl2b[cs1], a2 = wl2b[cs2];
#pragma unroll
        for (int j = 0; j < CS_; ++j) {
            float av = ashs[p][nb*17 + j];
            a1 = fmaf(wl2s[cs1*17 + j], av, a1);
            a2 = fmaf(wl2s[cs2*17 + j], av, a2);
        }
        wshs[p][nb*17 + cs1] = a1;
        wshs[p][nb*17 + cs2] = a2;
    }
    __syncthreads();

    // phase 4: softmax over nb per cs
    if (c < CS_) {
        float mx = -3e38f;
#pragma unroll
        for (int nb = 0; nb < K_; ++nb) mx = fmaxf(mx, wshs[p][nb*17 + c]);
        float ssum = 0.f;
#pragma unroll
        for (int nb = 0; nb < K_; ++nb) {
            float e = __expf(wshs[p][nb*17 + c] - mx);
            wshs[p][nb*17 + c] = e; ssum += e;
        }
        float inv = 1.f / ssum;
#pragma unroll
        for (int nb = 0; nb < K_; ++nb) wshs[p][nb*17 + c] *= inv;
    }
    __syncthreads();

    // phase 5: weighted aggregation + bn2 + relu
    float agg = 0.f;
    int cs = c & (CS_ - 1);
#pragma unroll
    for (int nb = 0; nb < K_; ++nb)
        agg = fmaf(svr[nb], wshs[p][nb*17 + cs], agg);
    float x2 = fmaxf(fmaf(agg, bn2g[c]*BNINV, bn2b[c]), 0.f);
    x2out[(size_t)bm * C_ + c] = x2;
}

// ---------------------------------------------------------------------------
// out[b][c][m] = relu(bn3(x2 @ l3w.T) + identity)   (transposed store)
extern "C" __global__ __launch_bounds__(256) void k_lin3(
    const float* __restrict__ x2, const float* __restrict__ w,
    const float* __restrict__ g, const float* __restrict__ bb,
    const float* __restrict__ xid, float* __restrict__ out)
{
    __shared__ float4 As4[32 * LDSA], Bs4[32 * LDSB];
    int t = threadIdx.x, tm = t >> 4, tn = t & 15;
    int m0 = blockIdx.x * 64;
    int b  = m0 >> 13;
    float acc[4][8] = {};
    for (int k0 = 0; k0 < C_; k0 += 32) {
        stage_transposeA((float*)As4, x2, m0, C_, k0, t);
        stage_transposeB((float*)Bs4, w, C_, k0, t);
        __syncthreads();
        gemm_step64(As4, Bs4, tm, tn, acc);
        __syncthreads();
    }
    int c0 = tn * 8;
    float gc[8], bc[8];
    load8(g + c0, gc); load8(bb + c0, bc);
#pragma unroll
    for (int mm = 0; mm < 4; ++mm) {
        int m = m0 + tm * 4 + mm;
        float idv[8];
        load8(xid + (size_t)m * C_ + c0, idv);
#pragma unroll
        for (int j = 0; j < 8; ++j) {
            float x3 = fmaf(acc[mm][j], gc[j] * BNINV, bc[j]);
            acc[mm][j] = fmaxf(x3 + idv[j], 0.f);
        }
    }
    int mloc = (m0 & (M_ - 1)) + tm * 4;
    float* ob = out + (size_t)b * C_ * M_;
#pragma unroll
    for (int j = 0; j < 8; ++j) {
        float* p = ob + (size_t)(c0 + j) * M_ + mloc;
        *(float4*)p = make_float4(acc[0][j], acc[1][j], acc[2][j], acc[3][j]);
    }
}

// ---------------------------------------------------------------------------
extern "C" void kernel_launch(void* const* d_in, const int* in_sizes, int n_in,
                              void* d_out, int out_size, void* d_ws, size_t ws_size,
                              hipStream_t stream)
{
    const float* xyz   = (const float*)d_in[0];
    const float* feat  = (const float*)d_in[1];
    const float* txyz  = (const float*)d_in[2];
    const float* tfeat = (const float*)d_in[3];
    const float* tu1w  = (const float*)d_in[4];
    const float* tu1g  = (const float*)d_in[5];
    const float* tu1b  = (const float*)d_in[6];
    const float* tu2w  = (const float*)d_in[7];
    const float* tu2g  = (const float*)d_in[8];
    const float* tu2b  = (const float*)d_in[9];
    const float* bl1w  = (const float*)d_in[10];
    const float* bl1g  = (const float*)d_in[11];
    const float* bl1b  = (const float*)d_in[12];
    const float* wq    = (const float*)d_in[13];
    const float* bq    = (const float*)d_in[14];
    const float* wk    = (const float*)d_in[15];
    const float* bk    = (const float*)d_in[16];
    const float* wv    = (const float*)d_in[17];
    const float* bv    = (const float*)d_in[18];
    const float* p1w   = (const float*)d_in[19];
    const float* p1b   = (const float*)d_in[20];
    const float* pbg   = (const float*)d_in[21];
    const float* pbb   = (const float*)d_in[22];
    const float* p2w   = (const float*)d_in[23];
    const float* p2b   = (const float*)d_in[24];
    const float* wb1g  = (const float*)d_in[25];
    const float* wb1b  = (const float*)d_in[26];
    const float* wl1   = (const float*)d_in[27];
    const float* wl1b  = (const float*)d_in[28];
    const float* wb2g  = (const float*)d_in[29];
    const float* wb2b  = (const float*)d_in[30];
    const float* wl2   = (const float*)d_in[31];
    const float* wl2b  = (const float*)d_in[32];
    const float* bn2g  = (const float*)d_in[33];
    const float* bn2b  = (const float*)d_in[34];
    const float* l3w   = (const float*)d_in[35];
    const float* bn3g  = (const float*)d_in[36];
    const float* bn3b  = (const float*)d_in[37];

    char* ws = (char*)d_ws;
    size_t off = 0;
    auto alloc = [&](size_t bytes) { void* p = ws + off; off += (bytes + 255) & ~(size_t)255; return p; };
    float* f_t  = (float*)alloc(sizeof(float) * B_ * N_ * C_);
    int*   idx3 = (int*)  alloc(sizeof(int)   * B_ * M_ * 3);
    float* w3   = (float*)alloc(sizeof(float) * B_ * M_ * 3);
    float* x    = (float*)alloc(sizeof(float) * B_ * M_ * C_);
    float* x2   = (float*)alloc(sizeof(float) * B_ * M_ * C_);
    float* qb   = (float*)alloc(sizeof(float) * B_ * M_ * C_);
    float* kb   = (float*)alloc(sizeof(float) * B_ * M_ * C_);
    float* vb   = (float*)alloc(sizeof(float) * B_ * M_ * C_);
    int*   knn  = (int*)  alloc(sizeof(int)   * B_ * M_ * K_);
    float* cx   = (float*)alloc(sizeof(float) * B_ * M_);
    float* cy   = (float*)alloc(sizeof(float) * B_ * M_);
    float* cz   = (float*)alloc(sizeof(float) * B_ * M_);

    k_soa     <<<(B_*M_+255)/256, 256, 0, stream>>>(txyz, cx, cy, cz);
    k_f       <<<B_*N_/64,        256, 0, stream>>>(feat, tu1w, tu1g, tu1b, f_t);
    k_three_nn<<<B_*M_/4,         256, 0, stream>>>(xyz, txyz, idx3, w3);
    k_feat    <<<B_*M_/64,        256, 0, stream>>>(tfeat, tu2w, tu2g, tu2b, f_t, idx3, w3, x);
    k_knn     <<<B_*M_/4,         256, 0, stream>>>(cx, cy, cz, knn);
    k_lqkv    <<<B_*M_/64,        256, 0, stream>>>(x, bl1w, bl1g, bl1b,
                                                    wq, bq, wk, bk, wv, bv, qb, kb, vb);
    k_attn2   <<<B_*M_/2,         256, 0, stream>>>(qb, kb, vb, knn, txyz,
                                                    p1w, p1b, pbg, pbb, p2w, p2b,
                                                    wb1g, wb1b, wl1, wl1b, wb2g, wb2b, wl2, wl2b,
                                                    bn2g, bn2b, x2);
    k_lin3    <<<B_*M_/64,        256, 0, stream>>>(x2, l3w, bn3g, bn3b, x, (float*)d_out);
}